// Round 3
// baseline (225.720 us; speedup 1.0000x reference)
//
#include <hip/hip_runtime.h>
#include <hip/hip_bf16.h>
#include <math.h>

#define BB 2
#define NN 8192
#define DD 512
#define HH 8
#define DK 64
#define KNB 32
#define BN (BB*NN)          // 16384 rows
#define BHN (BB*HH*NN)      // 131072 (b,h,n) tuples

typedef __attribute__((ext_vector_type(8))) _Float16 f16x8;   // 8 f16 in 4 VGPRs
typedef __attribute__((ext_vector_type(2))) _Float16 f16x2;
typedef __attribute__((ext_vector_type(4))) float f32x4;

#if __has_builtin(__builtin_amdgcn_fdot2)
#define HAS_FDOT2 1
#endif

__device__ __forceinline__ unsigned short f2h(float f) {
    return __builtin_bit_cast(unsigned short, (_Float16)f);
}
__device__ __forceinline__ f16x2 u2h2(unsigned u) {
    return __builtin_bit_cast(f16x2, u);
}
__device__ __forceinline__ float h2f_lo(unsigned u) {
    return (float)__builtin_bit_cast(_Float16, (unsigned short)(u & 0xffffu));
}
__device__ __forceinline__ float h2f_hi(unsigned u) {
    return (float)__builtin_bit_cast(_Float16, (unsigned short)(u >> 16));
}
// dot of packed f16 pairs with fp32 accumulate
__device__ __forceinline__ float dot2h(unsigned a, unsigned b, float c) {
#ifdef HAS_FDOT2
    return __builtin_amdgcn_fdot2(u2h2(a), u2h2(b), c, false);
#else
    c = fmaf(h2f_lo(a), h2f_lo(b), c);
    return fmaf(h2f_hi(a), h2f_hi(b), c);
#endif
}

// async global->LDS DMA. LDS dest is wave-uniform base; HW adds lane*width.
__device__ __forceinline__ void gload_lds16(const void* gptr, void* lptr) {
    __builtin_amdgcn_global_load_lds(
        (const __attribute__((address_space(1))) unsigned int*)gptr,
        (__attribute__((address_space(3))) unsigned int*)lptr,
        16, 0, 0);
}

// ---------------- fp32 -> f16 converter (x + all weights, one launch) ----------------
__global__ __launch_bounds__(256) void cvt_all(
    const float* __restrict__ x,
    const float* __restrict__ Wq, const float* __restrict__ Wk,
    const float* __restrict__ Wv, const float* __restrict__ Wo,
    unsigned short* __restrict__ Xb, unsigned short* __restrict__ Wfb,
    unsigned short* __restrict__ Wob)
{
    const int blk = blockIdx.x;
    const float* src;
    unsigned short* dst;
    int off;
    if (blk < 8192) {
        off = (blk * 256 + threadIdx.x) * 4;
        src = x; dst = Xb;
    } else {
        const int e = ((blk - 8192) * 256 + threadIdx.x) * 4;   // over 4*262144
        const int t = e >> 18;
        off = e & 262143;
        src = (t == 0) ? Wq : (t == 1) ? Wk : (t == 2) ? Wv : Wo;
        dst = (t < 3) ? (Wfb + (size_t)t * 262144) : Wob;
    }
    const float4 v = *(const float4*)(src + off);
    ushort4 u;
    u.x = f2h(v.x); u.y = f2h(v.y); u.z = f2h(v.z); u.w = f2h(v.w);
    *(ushort4*)(dst + off) = u;
}

// ---------------- Kernel 1: fused QKV projection + LayerNorm, f16 MFMA ----------------
__global__ __launch_bounds__(256) void gemm_qkv(
    const unsigned short* __restrict__ Xb, const unsigned short* __restrict__ Wfb,
    unsigned short* __restrict__ Qh, unsigned short* __restrict__ Kh,
    unsigned short* __restrict__ Vh)
{
    __shared__ unsigned short Als[128 * 32];   // 8 KB
    __shared__ unsigned short Bls[128 * 32];   // 8 KB
    const int tid  = threadIdx.x;
    const int wave = tid >> 6, lane = tid & 63;
    const int wm = wave >> 1, wn = wave & 1;
    const int quad = lane >> 4, r = lane & 15;
    const int row0 = blockIdx.x * 128;
    const int c0   = blockIdx.y * 128;        // 128 | 512 so tile is within one tensor

    f32x4 acc[4][4];
    #pragma unroll
    for (int i = 0; i < 4; ++i)
        #pragma unroll
        for (int j = 0; j < 4; ++j) acc[i][j] = (f32x4)0.f;

    const char* Ab = (const char*)Xb;
    const char* Bb = (const char*)Wfb;

    for (int k0 = 0; k0 < 512; k0 += 32) {
        __syncthreads();
        #pragma unroll
        for (int q = 0; q < 2; ++q) {
            const int li = q * 4096 + wave * 1024 + lane * 16;
            const int rr = li >> 6, off = li & 63;
            gload_lds16(Ab + (size_t)(row0 + rr) * 1024 + k0 * 2 + off,
                        (char*)Als + (q * 4096 + wave * 1024));
            gload_lds16(Bb + (size_t)(c0 + rr) * 1024 + k0 * 2 + off,
                        (char*)Bls + (q * 4096 + wave * 1024));
        }
        __syncthreads();

        f16x8 af[4], bf[4];
        #pragma unroll
        for (int i = 0; i < 4; ++i)
            af[i] = *(const f16x8*)(&Als[(wm * 64 + i * 16 + r) * 32 + quad * 8]);
        #pragma unroll
        for (int j = 0; j < 4; ++j)
            bf[j] = *(const f16x8*)(&Bls[(wn * 64 + j * 16 + r) * 32 + quad * 8]);
        #pragma unroll
        for (int i = 0; i < 4; ++i)
            #pragma unroll
            for (int j = 0; j < 4; ++j)
                acc[i][j] = __builtin_amdgcn_mfma_f32_16x16x32_f16(af[i], bf[j], acc[i][j], 0, 0, 0);
    }

    const int tensor = c0 >> 9;   // block-uniform: 0=Q 1=K 2=V
    unsigned short* OutH = (tensor == 0) ? Qh : (tensor == 1) ? Kh : Vh;

    float mu[4][4], rs[4][4];
    if (tensor < 2) {
        #pragma unroll
        for (int i = 0; i < 4; ++i) {
            #pragma unroll
            for (int reg = 0; reg < 4; ++reg) {
                float sm = acc[i][0][reg] + acc[i][1][reg] + acc[i][2][reg] + acc[i][3][reg];
                sm += __shfl_xor(sm, 1); sm += __shfl_xor(sm, 2);
                sm += __shfl_xor(sm, 4); sm += __shfl_xor(sm, 8);
                const float muv = sm * (1.f / 64.f);
                float qv = 0.f;
                #pragma unroll
                for (int j = 0; j < 4; ++j) {
                    const float dv = acc[i][j][reg] - muv;
                    qv = fmaf(dv, dv, qv);
                }
                qv += __shfl_xor(qv, 1); qv += __shfl_xor(qv, 2);
                qv += __shfl_xor(qv, 4); qv += __shfl_xor(qv, 8);
                mu[i][reg] = muv;
                rs[i][reg] = rsqrtf(qv * (1.f / 64.f) + 1e-5f);
            }
        }
    }

    // C/D layout col=lane&15, row=quad*4+reg (verified m89).
    #pragma unroll
    for (int i = 0; i < 4; ++i) {
        #pragma unroll
        for (int j = 0; j < 4; ++j) {
            const int cc = (c0 & 511) + wn * 64 + j * 16 + r;
            const int h = cc >> 6, d = cc & 63;
            #pragma unroll
            for (int reg = 0; reg < 4; ++reg) {
                const int row = row0 + wm * 64 + i * 16 + quad * 4 + reg;
                const int b = row >> 13, n = row & 8191;
                float v = acc[i][j][reg];
                if (tensor < 2) v = (v - mu[i][reg]) * rs[i][reg];
                OutH[(((size_t)(b * HH + h) * NN + n) << 6) + d] = f2h(v);
            }
        }
    }
}

// ---------------- Kernel 2: gather-attention, persistent-wave pipeline ----------------
// Round-2 bug: grid was BHN/16 = 8192 blocks for a kernel that covers 32 wids
// per block (4 waves x 8 tasks). Blocks p>=4096 ran wid0 past BHN (garbage
// gather reads) and wrapped n -> overwrote good outputs. Math path itself is
// bit-identical to the passing round-1 kernel. Fix: grid = BHN/32 = 4096.
// Pipeline (unchanged from round 2):
//   iter t: [DMA_t in flight] -> prefetch idx_{t+1} -> Q/K score loads for t
//   -> score+softmax -> issue DMA_{t+1} into other slab ->
//   s_waitcnt vmcnt(4) (counted; the only mid-loop wait) -> PV_t -> store.
// Mapping p in [0,4096): wid0 = (p&7)*16384 + (p>>3)*32 + wave*8, tasks +t
// (bijective over 0..131071; each XCD's 512 blocks touch 2 bh slabs = L2-local).
__global__ __launch_bounds__(256, 2) void attn(
    const unsigned short* __restrict__ Qh, const unsigned short* __restrict__ Kh,
    const unsigned short* __restrict__ Vh,
    const int* __restrict__ idx, unsigned short* __restrict__ Ob)
{
    __shared__ unsigned short Vls[4][2][2048];      // per-wave 2 slabs x 32 rows x 128 B
    const int p = blockIdx.x;                       // 0..4095
    const int wave = threadIdx.x >> 6;
    const int lane = threadIdx.x & 63;
    const int wid0 = ((p & 7) << 14) + ((p >> 3) << 5) + (wave << 3);
    const int bh = wid0 >> 13;
    const int n0 = wid0 & 8191;
    const size_t base = (size_t)bh * NN * DK;       // element offset of (b,h) slab

    char* s0 = (char*)Vls[wave][0];
    char* s1 = (char*)Vls[wave][1];
    const char* Vbytes = (const char*)Vh + (base << 1);
    const int col16 = (lane & 7) * 16;
    const int pa  = (lane >> 3) * 4;                // byte addr of my group's g
    const int k    = lane >> 1;
    const int half = lane & 1;
    const int c2 = lane & 31, h2 = lane >> 5;
    const int b = bh >> 3, hh = bh & 7;

    // prologue: idx + V-DMA for task 0 into slab 0
    int g_all = idx[n0 * KNB + (lane & 31)];
    #pragma unroll
    for (int j = 0; j < 4; ++j) {
        const int gv = __builtin_amdgcn_ds_bpermute(pa + j * 32, g_all);
        gload_lds16(Vbytes + (size_t)(gv * 128) + col16, s0 + j * 1024);
    }

    #pragma unroll
    for (int t = 0; t < 8; ++t) {
        const int n = n0 + t;
        char* cur = (t & 1) ? s1 : s0;
        char* nxt = (t & 1) ? s0 : s1;

        // prefetch idx for next task (latency hidden under this task's QK loads)
        int g_next = 0;
        if (t < 7) g_next = idx[(n + 1) * KNB + (lane & 31)];

        // score: half-row dot, 32 elements each, as 16 packed f16 pairs
        const int g = __builtin_amdgcn_ds_bpermute(k * 4, g_all);
        const uint4* q4 = (const uint4*)(Qh + base + ((size_t)n << 6) + half * 32);
        const uint4* k4 = (const uint4*)(Kh + base + ((size_t)g << 6) + half * 32);
        float acc = 0.f;
        #pragma unroll
        for (int c = 0; c < 4; ++c) {
            const uint4 qa = q4[c], ka = k4[c];
            acc = dot2h(qa.x, ka.x, acc);
            acc = dot2h(qa.y, ka.y, acc);
            acc = dot2h(qa.z, ka.z, acc);
            acc = dot2h(qa.w, ka.w, acc);
        }
        float s = (acc + __shfl_xor(acc, 1)) * 0.125f;   // 1/sqrt(64)

        // softmax over 32 distinct neighbors (values pair-duplicated)
        float m = s;
        #pragma unroll
        for (int off = 2; off <= 32; off <<= 1) m = fmaxf(m, __shfl_xor(m, off));
        const float e = __expf(s - m);
        float tot = e;
        #pragma unroll
        for (int off = 2; off <= 32; off <<= 1) tot += __shfl_xor(tot, off);
        const float pr = e / tot;

        // pack p pairs (f16): lane 4j holds p_{2j} | p_{2j+1}<<16
        const unsigned prh = (unsigned)f2h(pr);
        const unsigned pp = prh | (((unsigned)__shfl_xor((int)prh, 2)) << 16);

        // issue V-DMA for next task into the other slab, then counted wait:
        // leaves exactly the 4 new DMAs outstanding; everything earlier
        // (incl. DMA_t feeding this PV) is forced complete.
        if (t < 7) {
            #pragma unroll
            for (int j = 0; j < 4; ++j) {
                const int gv = __builtin_amdgcn_ds_bpermute(pa + j * 32, g_next);
                gload_lds16(Vbytes + (size_t)(gv * 128) + col16, nxt + j * 1024);
            }
            asm volatile("s_waitcnt vmcnt(4)" ::: "memory");
        } else {
            asm volatile("s_waitcnt vmcnt(0)" ::: "memory");
        }

        // PV: lane owns dims (2c,2c+1), rows 16*h2..16*h2+15
        const char* lb = cur + h2 * 2048 + c2 * 4;
        float o0 = 0.f, o1 = 0.f;
        #pragma unroll
        for (int j = 0; j < 8; ++j) {
            const unsigned vx = *(const unsigned*)(lb + j * 256);        // row 16h2+2j
            const unsigned vy = *(const unsigned*)(lb + j * 256 + 128);  // row 16h2+2j+1
            const unsigned ppj = (unsigned)__builtin_amdgcn_ds_bpermute(h2 * 128 + j * 16, (int)pp);
            const unsigned t0 = __builtin_amdgcn_perm(vx, vy, 0x01000504u); // (vx.lo, vy.lo)
            const unsigned t1 = __builtin_amdgcn_perm(vx, vy, 0x03020706u); // (vx.hi, vy.hi)
            o0 = dot2h(t0, ppj, o0);   // dim 2c
            o1 = dot2h(t1, ppj, o1);   // dim 2c+1
        }
        o0 += __shfl_xor(o0, 32);
        o1 += __shfl_xor(o1, 32);
        if (lane < 32) {
            const unsigned ov = (unsigned)f2h(o0) | ((unsigned)f2h(o1) << 16);
            *(unsigned*)(Ob + ((size_t)(b * NN + n)) * DD + hh * DK + 2 * c2) = ov;
        }
        g_all = g_next;
    }
}

// ---------------- Kernel 3: output projection, f16 MFMA ----------------
__global__ __launch_bounds__(256) void gemm_out(
    const unsigned short* __restrict__ Ob, const unsigned short* __restrict__ Wob,
    const float* __restrict__ bout, float* __restrict__ out)
{
    __shared__ unsigned short Als[128 * 32];
    __shared__ unsigned short Bls[128 * 32];
    const int tid  = threadIdx.x;
    const int wave = tid >> 6, lane = tid & 63;
    const int wm = wave >> 1, wn = wave & 1;
    const int quad = lane >> 4, r = lane & 15;
    const int row0 = blockIdx.x * 128;
    const int c0   = blockIdx.y * 128;

    f32x4 acc[4][4];
    #pragma unroll
    for (int i = 0; i < 4; ++i)
        #pragma unroll
        for (int j = 0; j < 4; ++j) acc[i][j] = (f32x4)0.f;

    const char* Ab = (const char*)Ob;
    const char* Bb = (const char*)Wob;

    for (int k0 = 0; k0 < 512; k0 += 32) {
        __syncthreads();
        #pragma unroll
        for (int q = 0; q < 2; ++q) {
            const int li = q * 4096 + wave * 1024 + lane * 16;
            const int rr = li >> 6, off = li & 63;
            gload_lds16(Ab + (size_t)(row0 + rr) * 1024 + k0 * 2 + off,
                        (char*)Als + (q * 4096 + wave * 1024));
            gload_lds16(Bb + (size_t)(c0 + rr) * 1024 + k0 * 2 + off,
                        (char*)Bls + (q * 4096 + wave * 1024));
        }
        __syncthreads();

        f16x8 af[4], bf[4];
        #pragma unroll
        for (int i = 0; i < 4; ++i)
            af[i] = *(const f16x8*)(&Als[(wm * 64 + i * 16 + r) * 32 + quad * 8]);
        #pragma unroll
        for (int j = 0; j < 4; ++j)
            bf[j] = *(const f16x8*)(&Bls[(wn * 64 + j * 16 + r) * 32 + quad * 8]);
        #pragma unroll
        for (int i = 0; i < 4; ++i)
            #pragma unroll
            for (int j = 0; j < 4; ++j)
                acc[i][j] = __builtin_amdgcn_mfma_f32_16x16x32_f16(af[i], bf[j], acc[i][j], 0, 0, 0);
    }

    #pragma unroll
    for (int i = 0; i < 4; ++i) {
        #pragma unroll
        for (int j = 0; j < 4; ++j) {
            const int colg = c0 + wn * 64 + j * 16 + r;
            const float bb = bout[colg];
            #pragma unroll
            for (int reg = 0; reg < 4; ++reg) {
                const int row = row0 + wm * 64 + i * 16 + quad * 4 + reg;
                out[((size_t)row << 9) + colg] = acc[i][j][reg] + bb;
            }
        }
    }
}

extern "C" void kernel_launch(void* const* d_in, const int* in_sizes, int n_in,
                              void* d_out, int out_size, void* d_ws, size_t ws_size,
                              hipStream_t stream)
{
    const float* x    = (const float*)d_in[0];
    const int*   idx  = (const int*)  d_in[1];
    const float* Wq   = (const float*)d_in[2];
    const float* Wk   = (const float*)d_in[3];
    const float* Wv   = (const float*)d_in[4];
    const float* Wout = (const float*)d_in[5];
    const float* bout = (const float*)d_in[6];

    char* ws = (char*)d_ws;
    unsigned short* Qh  = (unsigned short*)(ws);              // 16777216 B
    unsigned short* Kh  = (unsigned short*)(ws + 16777216);   // 16777216 B
    unsigned short* Vh  = (unsigned short*)(ws + 33554432);   // 16777216 B
    unsigned short* Xb  = (unsigned short*)(ws + 50331648);   // 16777216 B; aliased as Ob
    unsigned short* Ob  = Xb;
    unsigned short* Wfb = (unsigned short*)(ws + 67108864);   // 1572864 B (Wq|Wk|Wv rows)
    unsigned short* Wob = (unsigned short*)(ws + 68681728);   // 524288 B
    float* out = (float*)d_out;

    cvt_all<<<9216, 256, 0, stream>>>(x, Wq, Wk, Wv, Wout, Xb, Wfb, Wob);

    dim3 g1(BN / 128, 1536 / 128);
    gemm_qkv<<<g1, 256, 0, stream>>>(Xb, Wfb, Qh, Kh, Vh);

    attn<<<BHN / 32, 256, 0, stream>>>(Qh, Kh, Vh, idx, Ob);   // 4096 blocks: 4 waves x 8 tasks = 32 wids/block

    dim3 g2(BN / 128, 512 / 128);
    gemm_out<<<g2, 256, 0, stream>>>(Ob, Wob, bout, out);
}

// Round 4
// 224.934 us; speedup vs baseline: 1.0035x; 1.0035x over previous
//
#include <hip/hip_runtime.h>
#include <hip/hip_bf16.h>
#include <math.h>

#define BB 2
#define NN 8192
#define DD 512
#define HH 8
#define DK 64
#define KNB 32
#define BN (BB*NN)          // 16384 rows
#define BHN (BB*HH*NN)      // 131072 (b,h,n) tuples

typedef __attribute__((ext_vector_type(8))) _Float16 f16x8;   // 8 f16 in 4 VGPRs
typedef __attribute__((ext_vector_type(2))) _Float16 f16x2;
typedef __attribute__((ext_vector_type(4))) float f32x4;

#if __has_builtin(__builtin_amdgcn_fdot2)
#define HAS_FDOT2 1
#endif

__device__ __forceinline__ unsigned short f2h(float f) {
    return __builtin_bit_cast(unsigned short, (_Float16)f);
}
__device__ __forceinline__ f16x2 u2h2(unsigned u) {
    return __builtin_bit_cast(f16x2, u);
}
__device__ __forceinline__ float h2f_lo(unsigned u) {
    return (float)__builtin_bit_cast(_Float16, (unsigned short)(u & 0xffffu));
}
__device__ __forceinline__ float h2f_hi(unsigned u) {
    return (float)__builtin_bit_cast(_Float16, (unsigned short)(u >> 16));
}
// dot of packed f16 pairs with fp32 accumulate
__device__ __forceinline__ float dot2h(unsigned a, unsigned b, float c) {
#ifdef HAS_FDOT2
    return __builtin_amdgcn_fdot2(u2h2(a), u2h2(b), c, false);
#else
    c = fmaf(h2f_lo(a), h2f_lo(b), c);
    return fmaf(h2f_hi(a), h2f_hi(b), c);
#endif
}

// async global->LDS DMA. LDS dest is wave-uniform base; HW adds lane*width.
__device__ __forceinline__ void gload_lds16(const void* gptr, void* lptr) {
    __builtin_amdgcn_global_load_lds(
        (const __attribute__((address_space(1))) unsigned int*)gptr,
        (__attribute__((address_space(3))) unsigned int*)lptr,
        16, 0, 0);
}
__device__ __forceinline__ void gload_lds4(const void* gptr, void* lptr) {
    __builtin_amdgcn_global_load_lds(
        (const __attribute__((address_space(1))) unsigned int*)gptr,
        (__attribute__((address_space(3))) unsigned int*)lptr,
        4, 0, 0);
}

// ---------------- fp32 -> f16 converter (x + all weights, one launch) ----------------
__global__ __launch_bounds__(256) void cvt_all(
    const float* __restrict__ x,
    const float* __restrict__ Wq, const float* __restrict__ Wk,
    const float* __restrict__ Wv, const float* __restrict__ Wo,
    unsigned short* __restrict__ Xb, unsigned short* __restrict__ Wfb,
    unsigned short* __restrict__ Wob)
{
    const int blk = blockIdx.x;
    const float* src;
    unsigned short* dst;
    int off;
    if (blk < 8192) {
        off = (blk * 256 + threadIdx.x) * 4;
        src = x; dst = Xb;
    } else {
        const int e = ((blk - 8192) * 256 + threadIdx.x) * 4;   // over 4*262144
        const int t = e >> 18;
        off = e & 262143;
        src = (t == 0) ? Wq : (t == 1) ? Wk : (t == 2) ? Wv : Wo;
        dst = (t < 3) ? (Wfb + (size_t)t * 262144) : Wob;
    }
    const float4 v = *(const float4*)(src + off);
    ushort4 u;
    u.x = f2h(v.x); u.y = f2h(v.y); u.z = f2h(v.z); u.w = f2h(v.w);
    *(ushort4*)(dst + off) = u;
}

// ---------------- Kernel 1: fused QKV projection + LayerNorm, f16 MFMA ----------------
// Epilogue change this round: C-tile staged in LDS (stride 72 u16 to spread
// banks), then written as dwordx4 64-B coalesced runs into the (b,h,n,d)
// layout. Replaces 64 scalar u16 stores/thread scattered as 32-B segments.
// LN math and store values bit-identical to the previous passing version.
__global__ __launch_bounds__(256) void gemm_qkv(
    const unsigned short* __restrict__ Xb, const unsigned short* __restrict__ Wfb,
    unsigned short* __restrict__ Qh, unsigned short* __restrict__ Kh,
    unsigned short* __restrict__ Vh)
{
    __shared__ unsigned short Als[128 * 32];   // 8 KB
    __shared__ unsigned short Bls[128 * 32];   // 8 KB
    __shared__ unsigned short Cls[128 * 72];   // 18 KB epilogue staging
    const int tid  = threadIdx.x;
    const int wave = tid >> 6, lane = tid & 63;
    const int wm = wave >> 1, wn = wave & 1;
    const int quad = lane >> 4, r = lane & 15;
    const int row0 = blockIdx.x * 128;
    const int c0   = blockIdx.y * 128;        // 128 | 512 so tile is within one tensor

    f32x4 acc[4][4];
    #pragma unroll
    for (int i = 0; i < 4; ++i)
        #pragma unroll
        for (int j = 0; j < 4; ++j) acc[i][j] = (f32x4)0.f;

    const char* Ab = (const char*)Xb;
    const char* Bb = (const char*)Wfb;

    for (int k0 = 0; k0 < 512; k0 += 32) {
        __syncthreads();
        #pragma unroll
        for (int q = 0; q < 2; ++q) {
            const int li = q * 4096 + wave * 1024 + lane * 16;
            const int rr = li >> 6, off = li & 63;
            gload_lds16(Ab + (size_t)(row0 + rr) * 1024 + k0 * 2 + off,
                        (char*)Als + (q * 4096 + wave * 1024));
            gload_lds16(Bb + (size_t)(c0 + rr) * 1024 + k0 * 2 + off,
                        (char*)Bls + (q * 4096 + wave * 1024));
        }
        __syncthreads();

        f16x8 af[4], bf[4];
        #pragma unroll
        for (int i = 0; i < 4; ++i)
            af[i] = *(const f16x8*)(&Als[(wm * 64 + i * 16 + r) * 32 + quad * 8]);
        #pragma unroll
        for (int j = 0; j < 4; ++j)
            bf[j] = *(const f16x8*)(&Bls[(wn * 64 + j * 16 + r) * 32 + quad * 8]);
        #pragma unroll
        for (int i = 0; i < 4; ++i)
            #pragma unroll
            for (int j = 0; j < 4; ++j)
                acc[i][j] = __builtin_amdgcn_mfma_f32_16x16x32_f16(af[i], bf[j], acc[i][j], 0, 0, 0);
    }

    const int tensor = c0 >> 9;   // block-uniform: 0=Q 1=K 2=V
    unsigned short* OutH = (tensor == 0) ? Qh : (tensor == 1) ? Kh : Vh;

    float mu[4][4], rs[4][4];
    if (tensor < 2) {
        #pragma unroll
        for (int i = 0; i < 4; ++i) {
            #pragma unroll
            for (int reg = 0; reg < 4; ++reg) {
                float sm = acc[i][0][reg] + acc[i][1][reg] + acc[i][2][reg] + acc[i][3][reg];
                sm += __shfl_xor(sm, 1); sm += __shfl_xor(sm, 2);
                sm += __shfl_xor(sm, 4); sm += __shfl_xor(sm, 8);
                const float muv = sm * (1.f / 64.f);
                float qv = 0.f;
                #pragma unroll
                for (int j = 0; j < 4; ++j) {
                    const float dv = acc[i][j][reg] - muv;
                    qv = fmaf(dv, dv, qv);
                }
                qv += __shfl_xor(qv, 1); qv += __shfl_xor(qv, 2);
                qv += __shfl_xor(qv, 4); qv += __shfl_xor(qv, 8);
                mu[i][reg] = muv;
                rs[i][reg] = rsqrtf(qv * (1.f / 64.f) + 1e-5f);
            }
        }
    }

    // C/D layout col=lane&15, row=quad*4+reg (verified m89).
    // Stage cols [jh*32, jh*32+32) of every h-block per pass:
    //   actual cc = (c0&511) + wn*64 + j*16 + r,  j = jh*2+jj
    //   -> h = hbase + wn, d = jh*32 + (jj*16 + r)
    const int hbase = (c0 & 511) >> 6;
    const int row_b = row0 >> 13;                 // 128-row tile never straddles b
    const int nn0   = row0 & 8191;
    #pragma unroll
    for (int jh = 0; jh < 2; ++jh) {
        __syncthreads();                          // prev pass reads done / Cls free
        #pragma unroll
        for (int jj = 0; jj < 2; ++jj) {
            const int j = jh * 2 + jj;
            #pragma unroll
            for (int i = 0; i < 4; ++i) {
                #pragma unroll
                for (int reg = 0; reg < 4; ++reg) {
                    const int row = wm * 64 + i * 16 + quad * 4 + reg;
                    float v = acc[i][j][reg];
                    if (tensor < 2) v = (v - mu[i][reg]) * rs[i][reg];
                    Cls[row * 72 + wn * 32 + jj * 16 + r] = f2h(v);
                }
            }
        }
        __syncthreads();
        #pragma unroll
        for (int it = 0; it < 4; ++it) {
            const int e = (it * 256 + tid) * 8;   // over 128 rows x 64 cols u16
            const int row = e >> 6, col = e & 63;
            const int h_sub = col >> 5, dl = col & 31;
            const uint4 val = *(const uint4*)(&Cls[row * 72 + col]);
            const int h = hbase + h_sub;
            const int n = nn0 + row;
            *(uint4*)(OutH + (((size_t)(row_b * HH + h) * NN + n) << 6) + jh * 32 + dl) = val;
        }
    }
}

// ---------------- Kernel 2: gather-attention (round-1 version, known 76.0 us) ----------------
// Round-3 post-mortem: the persistent-wave pipeline LOST (80.6 us, occupancy
// 75->37%) -- for these tiny gather tasks, TLP (24 waves/CU of independent
// tasks) hides latency better than intra-wave ILP. Reverted to this version.
// One wave per (b,h,n):
//   * V staging: 4 width-16 global_load_lds DMAs (8 rows each, 128 contiguous
//     bytes per row); per-lane row index via ds_bpermute of canonical g layout.
//   * score phase (K gather + fdot2 + softmax) runs on top of the DMA.
//   * per-wave s_waitcnt vmcnt(0) (no block barrier), then PV reads LDS:
//     lane owns dim pair (2c,2c+1), dword reads (2-way alias = free),
//     v_perm repack, fdot2 f32 accumulate, shfl_xor(32) combine, dword store.
// XCD swizzle: physical block p -> logical (p&7)*4096 + (p>>3).
__global__ __launch_bounds__(256, 2) void attn(
    const unsigned short* __restrict__ Qh, const unsigned short* __restrict__ Kh,
    const unsigned short* __restrict__ Vh,
    const int* __restrict__ idx, unsigned short* __restrict__ Ob)
{
    __shared__ unsigned short Vls[4][2048];         // per-wave 32 rows x 128 B
    const int p = blockIdx.x;                       // 0..32767
    const int L = ((p & 7) << 12) | (p >> 3);       // XCD-contiguous logical id
    const int wave = threadIdx.x >> 6;
    const int wid  = L * 4 + wave;                  // 0..BHN-1
    const int lane = threadIdx.x & 63;
    const int bh = wid >> 13;
    const int n  = wid & 8191;
    const size_t base = (size_t)bh * NN * DK;       // element offset of (b,h) slab

    // canonical neighbor layout: lane l holds g_l (l<32; upper half duplicates)
    const int g_all = idx[n * KNB + (lane & 31)];

    // Phase 1: stage all 32 V rows. DMA j: lanes 8m..8m+7 fetch the 128 B of
    // row g_{8j+m}; instruction writes 1 KB at lw + j*1024 (rows at lw + r*128).
    char* lw = (char*)Vls[wave];
    const char* Vbytes = (const char*)Vh + (base << 1);
    const int col16 = (lane & 7) * 16;
    const int pa = (lane >> 3) * 4;                 // byte addr of my group's g
    #pragma unroll
    for (int j = 0; j < 4; ++j) {
        const int gv = __builtin_amdgcn_ds_bpermute(pa + j * 32, g_all);
        gload_lds16(Vbytes + (size_t)(gv * 128) + col16, lw + j * 1024);
    }

    // Phase 2: score. Half-row dot: 32 elements each, as 16 packed f16 pairs.
    const int k    = lane >> 1;
    const int half = lane & 1;
    const int g    = __builtin_amdgcn_ds_bpermute(k * 4, g_all);

    const uint4* q4 = (const uint4*)(Qh + base + ((size_t)n << 6) + half * 32);
    const uint4* k4 = (const uint4*)(Kh + base + ((size_t)g << 6) + half * 32);
    float acc = 0.f;
    #pragma unroll
    for (int c = 0; c < 4; ++c) {
        const uint4 qa = q4[c], ka = k4[c];
        acc = dot2h(qa.x, ka.x, acc);
        acc = dot2h(qa.y, ka.y, acc);
        acc = dot2h(qa.z, ka.z, acc);
        acc = dot2h(qa.w, ka.w, acc);
    }
    float s = (acc + __shfl_xor(acc, 1)) * 0.125f;  // 1/sqrt(64)

    // softmax over 32 distinct neighbors (values pair-duplicated):
    float m = s;
    #pragma unroll
    for (int off = 2; off <= 32; off <<= 1) m = fmaxf(m, __shfl_xor(m, off));
    const float e = __expf(s - m);
    float tot = e;
    #pragma unroll
    for (int off = 2; off <= 32; off <<= 1) tot += __shfl_xor(tot, off);
    const float pr = e / tot;

    // Pack p pairs (f16): lane 4j holds p_{2j} | p_{2j+1}<<16.
    const unsigned prh = (unsigned)f2h(pr);
    const unsigned pp = prh | (((unsigned)__shfl_xor((int)prh, 2)) << 16);

    // Phase 3: make this wave's DMAs visible (per-wave, no block barrier).
    asm volatile("s_waitcnt vmcnt(0)" ::: "memory");

    // Lane owns dims (2c, 2c+1), rows 16*h2 .. 16*h2+15.
    const int c2 = lane & 31, h2 = lane >> 5;
    const char* lb = lw + h2 * 2048 + c2 * 4;
    float o0 = 0.f, o1 = 0.f;
    #pragma unroll
    for (int j = 0; j < 8; ++j) {
        const unsigned vx = *(const unsigned*)(lb + j * 256);        // row 16h2+2j
        const unsigned vy = *(const unsigned*)(lb + j * 256 + 128);  // row 16h2+2j+1
        // p pair for rows (16h2+2j, 16h2+2j+1) lives at lane 32h2+4j.
        const unsigned ppj = (unsigned)__builtin_amdgcn_ds_bpermute(h2 * 128 + j * 16, (int)pp);
        const unsigned t0 = __builtin_amdgcn_perm(vx, vy, 0x01000504u); // (vx.lo, vy.lo)
        const unsigned t1 = __builtin_amdgcn_perm(vx, vy, 0x03020706u); // (vx.hi, vy.hi)
        o0 = dot2h(t0, ppj, o0);   // dim 2c
        o1 = dot2h(t1, ppj, o1);   // dim 2c+1
    }
    o0 += __shfl_xor(o0, 32);
    o1 += __shfl_xor(o1, 32);
    if (lane < 32) {
        const int b = bh >> 3, hh = bh & 7;
        const unsigned ov = (unsigned)f2h(o0) | ((unsigned)f2h(o1) << 16);
        *(unsigned*)(Ob + ((size_t)(b * NN + n)) * DD + hh * DK + 2 * c2) = ov;
    }
}

// ---------------- Kernel 3: output projection, f16 MFMA ----------------
__global__ __launch_bounds__(256) void gemm_out(
    const unsigned short* __restrict__ Ob, const unsigned short* __restrict__ Wob,
    const float* __restrict__ bout, float* __restrict__ out)
{
    __shared__ unsigned short Als[128 * 32];
    __shared__ unsigned short Bls[128 * 32];
    const int tid  = threadIdx.x;
    const int wave = tid >> 6, lane = tid & 63;
    const int wm = wave >> 1, wn = wave & 1;
    const int quad = lane >> 4, r = lane & 15;
    const int row0 = blockIdx.x * 128;
    const int c0   = blockIdx.y * 128;

    f32x4 acc[4][4];
    #pragma unroll
    for (int i = 0; i < 4; ++i)
        #pragma unroll
        for (int j = 0; j < 4; ++j) acc[i][j] = (f32x4)0.f;

    const char* Ab = (const char*)Ob;
    const char* Bb = (const char*)Wob;

    for (int k0 = 0; k0 < 512; k0 += 32) {
        __syncthreads();
        #pragma unroll
        for (int q = 0; q < 2; ++q) {
            const int li = q * 4096 + wave * 1024 + lane * 16;
            const int rr = li >> 6, off = li & 63;
            gload_lds16(Ab + (size_t)(row0 + rr) * 1024 + k0 * 2 + off,
                        (char*)Als + (q * 4096 + wave * 1024));
            gload_lds16(Bb + (size_t)(c0 + rr) * 1024 + k0 * 2 + off,
                        (char*)Bls + (q * 4096 + wave * 1024));
        }
        __syncthreads();

        f16x8 af[4], bf[4];
        #pragma unroll
        for (int i = 0; i < 4; ++i)
            af[i] = *(const f16x8*)(&Als[(wm * 64 + i * 16 + r) * 32 + quad * 8]);
        #pragma unroll
        for (int j = 0; j < 4; ++j)
            bf[j] = *(const f16x8*)(&Bls[(wn * 64 + j * 16 + r) * 32 + quad * 8]);
        #pragma unroll
        for (int i = 0; i < 4; ++i)
            #pragma unroll
            for (int j = 0; j < 4; ++j)
                acc[i][j] = __builtin_amdgcn_mfma_f32_16x16x32_f16(af[i], bf[j], acc[i][j], 0, 0, 0);
    }

    #pragma unroll
    for (int i = 0; i < 4; ++i) {
        #pragma unroll
        for (int j = 0; j < 4; ++j) {
            const int colg = c0 + wn * 64 + j * 16 + r;
            const float bb = bout[colg];
            #pragma unroll
            for (int reg = 0; reg < 4; ++reg) {
                const int row = row0 + wm * 64 + i * 16 + quad * 4 + reg;
                out[((size_t)row << 9) + colg] = acc[i][j][reg] + bb;
            }
        }
    }
}

extern "C" void kernel_launch(void* const* d_in, const int* in_sizes, int n_in,
                              void* d_out, int out_size, void* d_ws, size_t ws_size,
                              hipStream_t stream)
{
    const float* x    = (const float*)d_in[0];
    const int*   idx  = (const int*)  d_in[1];
    const float* Wq   = (const float*)d_in[2];
    const float* Wk   = (const float*)d_in[3];
    const float* Wv   = (const float*)d_in[4];
    const float* Wout = (const float*)d_in[5];
    const float* bout = (const float*)d_in[6];

    char* ws = (char*)d_ws;
    unsigned short* Qh  = (unsigned short*)(ws);              // 16777216 B
    unsigned short* Kh  = (unsigned short*)(ws + 16777216);   // 16777216 B
    unsigned short* Vh  = (unsigned short*)(ws + 33554432);   // 16777216 B
    unsigned short* Xb  = (unsigned short*)(ws + 50331648);   // 16777216 B; aliased as Ob
    unsigned short* Ob  = Xb;
    unsigned short* Wfb = (unsigned short*)(ws + 67108864);   // 1572864 B (Wq|Wk|Wv rows)
    unsigned short* Wob = (unsigned short*)(ws + 68681728);   // 524288 B
    float* out = (float*)d_out;

    cvt_all<<<9216, 256, 0, stream>>>(x, Wq, Wk, Wv, Wout, Xb, Wfb, Wob);

    dim3 g1(BN / 128, 1536 / 128);
    gemm_qkv<<<g1, 256, 0, stream>>>(Xb, Wfb, Qh, Kh, Vh);

    attn<<<BHN / 4, 256, 0, stream>>>(Qh, Kh, Vh, idx, Ob);

    dim3 g2(BN / 128, 512 / 128);
    gemm_out<<<g2, 256, 0, stream>>>(Ob, Wob, bout, out);
}

// Round 6
// 219.795 us; speedup vs baseline: 1.0270x; 1.0234x over previous
//
#include <hip/hip_runtime.h>
#include <hip/hip_bf16.h>
#include <math.h>

#define BB 2
#define NN 8192
#define DD 512
#define HH 8
#define DK 64
#define KNB 32
#define BN (BB*NN)          // 16384 rows
#define BHN (BB*HH*NN)      // 131072 (b,h,n) tuples

typedef __attribute__((ext_vector_type(8))) _Float16 f16x8;   // 8 f16 in 4 VGPRs
typedef __attribute__((ext_vector_type(2))) _Float16 f16x2;
typedef __attribute__((ext_vector_type(4))) float f32x4;

#if __has_builtin(__builtin_amdgcn_fdot2)
#define HAS_FDOT2 1
#endif

__device__ __forceinline__ unsigned short f2h(float f) {
    return __builtin_bit_cast(unsigned short, (_Float16)f);
}
__device__ __forceinline__ f16x2 u2h2(unsigned u) {
    return __builtin_bit_cast(f16x2, u);
}
__device__ __forceinline__ float h2f_lo(unsigned u) {
    return (float)__builtin_bit_cast(_Float16, (unsigned short)(u & 0xffffu));
}
__device__ __forceinline__ float h2f_hi(unsigned u) {
    return (float)__builtin_bit_cast(_Float16, (unsigned short)(u >> 16));
}
// dot of packed f16 pairs with fp32 accumulate
__device__ __forceinline__ float dot2h(unsigned a, unsigned b, float c) {
#ifdef HAS_FDOT2
    return __builtin_amdgcn_fdot2(u2h2(a), u2h2(b), c, false);
#else
    c = fmaf(h2f_lo(a), h2f_lo(b), c);
    return fmaf(h2f_hi(a), h2f_hi(b), c);
#endif
}

// async global->LDS DMA. LDS dest is wave-uniform base; HW adds lane*width.
__device__ __forceinline__ void gload_lds16(const void* gptr, void* lptr) {
    __builtin_amdgcn_global_load_lds(
        (const __attribute__((address_space(1))) unsigned int*)gptr,
        (__attribute__((address_space(3))) unsigned int*)lptr,
        16, 0, 0);
}

// ---------------- fp32 -> f16 converter (x + all weights, one launch) ----------------
__global__ __launch_bounds__(256) void cvt_all(
    const float* __restrict__ x,
    const float* __restrict__ Wq, const float* __restrict__ Wk,
    const float* __restrict__ Wv, const float* __restrict__ Wo,
    unsigned short* __restrict__ Xb, unsigned short* __restrict__ Wfb,
    unsigned short* __restrict__ Wob)
{
    const int blk = blockIdx.x;
    const float* src;
    unsigned short* dst;
    int off;
    if (blk < 8192) {
        off = (blk * 256 + threadIdx.x) * 4;
        src = x; dst = Xb;
    } else {
        const int e = ((blk - 8192) * 256 + threadIdx.x) * 4;   // over 4*262144
        const int t = e >> 18;
        off = e & 262143;
        src = (t == 0) ? Wq : (t == 1) ? Wk : (t == 2) ? Wv : Wo;
        dst = (t < 3) ? (Wfb + (size_t)t * 262144) : Wob;
    }
    const float4 v = *(const float4*)(src + off);
    ushort4 u;
    u.x = f2h(v.x); u.y = f2h(v.y); u.z = f2h(v.z); u.w = f2h(v.w);
    *(ushort4*)(dst + off) = u;
}

// ---------------- Kernel 1: fused QKV projection + LayerNorm, f16 MFMA ----------------
// Round-4 post-mortem: the LDS-staged epilogue was neutral-to-negative
// (+3 us total). Reverted to the round-1 scalar-store epilogue.
__global__ __launch_bounds__(256) void gemm_qkv(
    const unsigned short* __restrict__ Xb, const unsigned short* __restrict__ Wfb,
    unsigned short* __restrict__ Qh, unsigned short* __restrict__ Kh,
    unsigned short* __restrict__ Vh)
{
    __shared__ unsigned short Als[128 * 32];   // 8 KB
    __shared__ unsigned short Bls[128 * 32];   // 8 KB
    const int tid  = threadIdx.x;
    const int wave = tid >> 6, lane = tid & 63;
    const int wm = wave >> 1, wn = wave & 1;
    const int quad = lane >> 4, r = lane & 15;
    const int row0 = blockIdx.x * 128;
    const int c0   = blockIdx.y * 128;        // 128 | 512 so tile is within one tensor

    f32x4 acc[4][4];
    #pragma unroll
    for (int i = 0; i < 4; ++i)
        #pragma unroll
        for (int j = 0; j < 4; ++j) acc[i][j] = (f32x4)0.f;

    const char* Ab = (const char*)Xb;
    const char* Bb = (const char*)Wfb;

    for (int k0 = 0; k0 < 512; k0 += 32) {
        __syncthreads();
        #pragma unroll
        for (int q = 0; q < 2; ++q) {
            const int li = q * 4096 + wave * 1024 + lane * 16;
            const int rr = li >> 6, off = li & 63;
            gload_lds16(Ab + (size_t)(row0 + rr) * 1024 + k0 * 2 + off,
                        (char*)Als + (q * 4096 + wave * 1024));
            gload_lds16(Bb + (size_t)(c0 + rr) * 1024 + k0 * 2 + off,
                        (char*)Bls + (q * 4096 + wave * 1024));
        }
        __syncthreads();

        f16x8 af[4], bf[4];
        #pragma unroll
        for (int i = 0; i < 4; ++i)
            af[i] = *(const f16x8*)(&Als[(wm * 64 + i * 16 + r) * 32 + quad * 8]);
        #pragma unroll
        for (int j = 0; j < 4; ++j)
            bf[j] = *(const f16x8*)(&Bls[(wn * 64 + j * 16 + r) * 32 + quad * 8]);
        #pragma unroll
        for (int i = 0; i < 4; ++i)
            #pragma unroll
            for (int j = 0; j < 4; ++j)
                acc[i][j] = __builtin_amdgcn_mfma_f32_16x16x32_f16(af[i], bf[j], acc[i][j], 0, 0, 0);
    }

    const int tensor = c0 >> 9;   // block-uniform: 0=Q 1=K 2=V
    unsigned short* OutH = (tensor == 0) ? Qh : (tensor == 1) ? Kh : Vh;

    float mu[4][4], rs[4][4];
    if (tensor < 2) {
        #pragma unroll
        for (int i = 0; i < 4; ++i) {
            #pragma unroll
            for (int reg = 0; reg < 4; ++reg) {
                float sm = acc[i][0][reg] + acc[i][1][reg] + acc[i][2][reg] + acc[i][3][reg];
                sm += __shfl_xor(sm, 1); sm += __shfl_xor(sm, 2);
                sm += __shfl_xor(sm, 4); sm += __shfl_xor(sm, 8);
                const float muv = sm * (1.f / 64.f);
                float qv = 0.f;
                #pragma unroll
                for (int j = 0; j < 4; ++j) {
                    const float dv = acc[i][j][reg] - muv;
                    qv = fmaf(dv, dv, qv);
                }
                qv += __shfl_xor(qv, 1); qv += __shfl_xor(qv, 2);
                qv += __shfl_xor(qv, 4); qv += __shfl_xor(qv, 8);
                mu[i][reg] = muv;
                rs[i][reg] = rsqrtf(qv * (1.f / 64.f) + 1e-5f);
            }
        }
    }

    // C/D layout col=lane&15, row=quad*4+reg (verified m89).
    #pragma unroll
    for (int i = 0; i < 4; ++i) {
        #pragma unroll
        for (int j = 0; j < 4; ++j) {
            const int cc = (c0 & 511) + wn * 64 + j * 16 + r;
            const int h = cc >> 6, d = cc & 63;
            #pragma unroll
            for (int reg = 0; reg < 4; ++reg) {
                const int row = row0 + wm * 64 + i * 16 + quad * 4 + reg;
                const int b = row >> 13, n = row & 8191;
                float v = acc[i][j][reg];
                if (tensor < 2) v = (v - mu[i][reg]) * rs[i][reg];
                OutH[(((size_t)(b * HH + h) * NN + n) << 6) + d] = f2h(v);
            }
        }
    }
}

// ---------------- Kernel 2: gather-attention, zero-LDS direct-from-L2 PV ----------------
// (Resubmission of round 5 -- container infra failure, never measured.)
// Round-4 counters (reverted state): 76 us, VALUBusy 52%, occupancy 74%,
// bank-conflict 0, HBM 8%. The V slab per (b,h) is 1 MB -> L2-resident
// (XCD swizzle gives each XCD 2 slabs = 4 MB K+V in its own L2). Per
// Common-mistake #7, LDS-staging L2-fit data is overhead. This round:
//   * PV reads V rows DIRECTLY from global: lanes 0..31 read 128 contiguous
//     bytes of one row (one L2 segment), lanes 32..63 another row. Same
//     traffic as the DMA, minus the LDS write+read round-trip, minus the
//     DMA-issue code, minus the vmcnt(0) serialization before PV.
//   * score accumulator split into 2 chains (halves the serial fdot2 chain).
//   * softmax max-subtraction dropped: LN'd rows => |s| <= ~8.03
//     (Cauchy-Schwarz) => e^s <= 3.1e3, f32-safe; pr identical up to rounding.
//   * attn LDS usage -> 0 (watch LDS_Block_Size in counters).
// XCD swizzle: physical block p -> logical (p&7)*4096 + (p>>3).
__global__ __launch_bounds__(256, 2) void attn(
    const unsigned short* __restrict__ Qh, const unsigned short* __restrict__ Kh,
    const unsigned short* __restrict__ Vh,
    const int* __restrict__ idx, unsigned short* __restrict__ Ob)
{
    const int p = blockIdx.x;                       // 0..32767
    const int L = ((p & 7) << 12) | (p >> 3);       // XCD-contiguous logical id
    const int wave = threadIdx.x >> 6;
    const int wid  = L * 4 + wave;                  // 0..BHN-1
    const int lane = threadIdx.x & 63;
    const int bh = wid >> 13;
    const int n  = wid & 8191;
    const size_t base = (size_t)bh * NN * DK;       // element offset of (b,h) slab

    // canonical neighbor layout: lane l holds g_l (l<32; upper half duplicates)
    const int g_all = idx[n * KNB + (lane & 31)];

    // Score. Half-row dot: 32 elements each, as 16 packed f16 pairs, 2 chains.
    const int k    = lane >> 1;
    const int half = lane & 1;
    const int g    = __builtin_amdgcn_ds_bpermute(k * 4, g_all);

    const uint4* q4 = (const uint4*)(Qh + base + ((size_t)n << 6) + half * 32);
    const uint4* k4 = (const uint4*)(Kh + base + ((size_t)g << 6) + half * 32);
    float a0 = 0.f, a1 = 0.f;
    {
        const uint4 qa = q4[0], ka = k4[0];
        a0 = dot2h(qa.x, ka.x, a0); a0 = dot2h(qa.y, ka.y, a0);
        a0 = dot2h(qa.z, ka.z, a0); a0 = dot2h(qa.w, ka.w, a0);
    }
    {
        const uint4 qa = q4[1], ka = k4[1];
        a1 = dot2h(qa.x, ka.x, a1); a1 = dot2h(qa.y, ka.y, a1);
        a1 = dot2h(qa.z, ka.z, a1); a1 = dot2h(qa.w, ka.w, a1);
    }
    {
        const uint4 qa = q4[2], ka = k4[2];
        a0 = dot2h(qa.x, ka.x, a0); a0 = dot2h(qa.y, ka.y, a0);
        a0 = dot2h(qa.z, ka.z, a0); a0 = dot2h(qa.w, ka.w, a0);
    }
    {
        const uint4 qa = q4[3], ka = k4[3];
        a1 = dot2h(qa.x, ka.x, a1); a1 = dot2h(qa.y, ka.y, a1);
        a1 = dot2h(qa.z, ka.z, a1); a1 = dot2h(qa.w, ka.w, a1);
    }
    const float acc = a0 + a1;
    const float s = (acc + __shfl_xor(acc, 1)) * 0.125f;  // 1/sqrt(64)

    // softmax over 32 distinct neighbors (values pair-duplicated); no max
    // subtraction needed: |s| <= ~8.03 (LN'd rows), e^s <= 3.1e3 in f32.
    const float e = __expf(s);
    float tot = e;
    #pragma unroll
    for (int off = 2; off <= 32; off <<= 1) tot += __shfl_xor(tot, off);
    const float pr = e / tot;

    // Pack p pairs (f16): lane 4j holds p_{2j} | p_{2j+1}<<16.
    const unsigned prh = (unsigned)f2h(pr);
    const unsigned pp = prh | (((unsigned)__shfl_xor((int)prh, 2)) << 16);

    // PV, direct from global/L2. Lane owns dims (2c,2c+1); half h2 handles
    // rows 16*h2 .. 16*h2+15 (8 pairs). Per pair: two dword loads (each a
    // 128-B coalesced segment per half-wave), v_perm repack, 2 fdot2 chains.
    const char* Vbytes = (const char*)Vh + (base << 1);
    const int c2 = lane & 31, h2 = lane >> 5;
    float o0 = 0.f, o1 = 0.f;
    #pragma unroll
    for (int j = 0; j < 8; ++j) {
        const int r0 = __builtin_amdgcn_ds_bpermute((h2 * 16 + 2 * j) * 4, g_all);
        const int r1 = __builtin_amdgcn_ds_bpermute((h2 * 16 + 2 * j + 1) * 4, g_all);
        const unsigned vx = *(const unsigned*)(Vbytes + (size_t)(r0 * 128) + c2 * 4); // row 16h2+2j
        const unsigned vy = *(const unsigned*)(Vbytes + (size_t)(r1 * 128) + c2 * 4); // row 16h2+2j+1
        // p pair for rows (16h2+2j, 16h2+2j+1) lives at lane 32h2+4j.
        const unsigned ppj = (unsigned)__builtin_amdgcn_ds_bpermute(h2 * 128 + j * 16, (int)pp);
        const unsigned t0 = __builtin_amdgcn_perm(vx, vy, 0x01000504u); // (vx.lo, vy.lo)
        const unsigned t1 = __builtin_amdgcn_perm(vx, vy, 0x03020706u); // (vx.hi, vy.hi)
        o0 = dot2h(t0, ppj, o0);   // dim 2c
        o1 = dot2h(t1, ppj, o1);   // dim 2c+1
    }
    o0 += __shfl_xor(o0, 32);
    o1 += __shfl_xor(o1, 32);
    if (lane < 32) {
        const int b = bh >> 3, hh = bh & 7;
        const unsigned ov = (unsigned)f2h(o0) | ((unsigned)f2h(o1) << 16);
        *(unsigned*)(Ob + ((size_t)(b * NN + n)) * DD + hh * DK + 2 * c2) = ov;
    }
}

// ---------------- Kernel 3: output projection, f16 MFMA ----------------
__global__ __launch_bounds__(256) void gemm_out(
    const unsigned short* __restrict__ Ob, const unsigned short* __restrict__ Wob,
    const float* __restrict__ bout, float* __restrict__ out)
{
    __shared__ unsigned short Als[128 * 32];
    __shared__ unsigned short Bls[128 * 32];
    const int tid  = threadIdx.x;
    const int wave = tid >> 6, lane = tid & 63;
    const int wm = wave >> 1, wn = wave & 1;
    const int quad = lane >> 4, r = lane & 15;
    const int row0 = blockIdx.x * 128;
    const int c0   = blockIdx.y * 128;

    f32x4 acc[4][4];
    #pragma unroll
    for (int i = 0; i < 4; ++i)
        #pragma unroll
        for (int j = 0; j < 4; ++j) acc[i][j] = (f32x4)0.f;

    const char* Ab = (const char*)Ob;
    const char* Bb = (const char*)Wob;

    for (int k0 = 0; k0 < 512; k0 += 32) {
        __syncthreads();
        #pragma unroll
        for (int q = 0; q < 2; ++q) {
            const int li = q * 4096 + wave * 1024 + lane * 16;
            const int rr = li >> 6, off = li & 63;
            gload_lds16(Ab + (size_t)(row0 + rr) * 1024 + k0 * 2 + off,
                        (char*)Als + (q * 4096 + wave * 1024));
            gload_lds16(Bb + (size_t)(c0 + rr) * 1024 + k0 * 2 + off,
                        (char*)Bls + (q * 4096 + wave * 1024));
        }
        __syncthreads();

        f16x8 af[4], bf[4];
        #pragma unroll
        for (int i = 0; i < 4; ++i)
            af[i] = *(const f16x8*)(&Als[(wm * 64 + i * 16 + r) * 32 + quad * 8]);
        #pragma unroll
        for (int j = 0; j < 4; ++j)
            bf[j] = *(const f16x8*)(&Bls[(wn * 64 + j * 16 + r) * 32 + quad * 8]);
        #pragma unroll
        for (int i = 0; i < 4; ++i)
            #pragma unroll
            for (int j = 0; j < 4; ++j)
                acc[i][j] = __builtin_amdgcn_mfma_f32_16x16x32_f16(af[i], bf[j], acc[i][j], 0, 0, 0);
    }

    #pragma unroll
    for (int i = 0; i < 4; ++i) {
        #pragma unroll
        for (int j = 0; j < 4; ++j) {
            const int colg = c0 + wn * 64 + j * 16 + r;
            const float bb = bout[colg];
            #pragma unroll
            for (int reg = 0; reg < 4; ++reg) {
                const int row = row0 + wm * 64 + i * 16 + quad * 4 + reg;
                out[((size_t)row << 9) + colg] = acc[i][j][reg] + bb;
            }
        }
    }
}

extern "C" void kernel_launch(void* const* d_in, const int* in_sizes, int n_in,
                              void* d_out, int out_size, void* d_ws, size_t ws_size,
                              hipStream_t stream)
{
    const float* x    = (const float*)d_in[0];
    const int*   idx  = (const int*)  d_in[1];
    const float* Wq   = (const float*)d_in[2];
    const float* Wk   = (const float*)d_in[3];
    const float* Wv   = (const float*)d_in[4];
    const float* Wout = (const float*)d_in[5];
    const float* bout = (const float*)d_in[6];

    char* ws = (char*)d_ws;
    unsigned short* Qh  = (unsigned short*)(ws);              // 16777216 B
    unsigned short* Kh  = (unsigned short*)(ws + 16777216);   // 16777216 B
    unsigned short* Vh  = (unsigned short*)(ws + 33554432);   // 16777216 B
    unsigned short* Xb  = (unsigned short*)(ws + 50331648);   // 16777216 B; aliased as Ob
    unsigned short* Ob  = Xb;
    unsigned short* Wfb = (unsigned short*)(ws + 67108864);   // 1572864 B (Wq|Wk|Wv rows)
    unsigned short* Wob = (unsigned short*)(ws + 68681728);   // 524288 B
    float* out = (float*)d_out;

    cvt_all<<<9216, 256, 0, stream>>>(x, Wq, Wk, Wv, Wout, Xb, Wfb, Wob);

    dim3 g1(BN / 128, 1536 / 128);
    gemm_qkv<<<g1, 256, 0, stream>>>(Xb, Wfb, Qh, Kh, Vh);

    attn<<<BHN / 4, 256, 0, stream>>>(Qh, Kh, Vh, idx, Ob);

    dim3 g2(BN / 128, 512 / 128);
    gemm_out<<<g2, 256, 0, stream>>>(Ob, Wob, bout, out);
}